// Round 1
// baseline (439.392 us; speedup 1.0000x reference)
//
#include <hip/hip_runtime.h>

// IIR filtfilt via overlap-chunk parallelization.
// Max pole radius ~0.924 -> WARM=96 warm-up truncates initial-state error to
// ~0.924^96 ~ 5e-4 relative (~2.5e-3 abs), far below the 6e-2 threshold.
// R3: CHUNK 256->64, WARM 192->96. R2 was latency-bound at 2 waves/SIMD
// (Occupancy 20%, VALUBusy 17.6%, HBM 2.7/6.3 TB/s): grid had only 2048
// waves for 1024 SIMDs. 4x thread count -> 8 waves/SIMD (VGPR=40 permits
// full residency); redundant warm-up compute is cheap (VALU 82% idle).
constexpr int CHUNK = 64;    // output samples per thread
constexpr int WARM  = 96;    // warm-up samples (discarded); multiple of 16
constexpr int BATCH = 16;    // samples per prefetch batch (4 x float4)

// DIR=0: forward in time. DIR=1: process time-reversed sequence
// (reads/writes at mirrored positions T-1-t).
template <int DIR>
__global__ __launch_bounds__(256) void iir_pass(
    const float* __restrict__ x, float* __restrict__ y,
    const float* __restrict__ bc, const float* __restrict__ ac,
    int T, int chunksPerRow)
{
    const int gid   = blockIdx.x * blockDim.x + threadIdx.x;
    const int row   = gid / chunksPerRow;
    const int chunk = gid - row * chunksPerRow;

    const float* __restrict__ xr = x + (size_t)row * T;
    float* __restrict__       yr = y + (size_t)row * T;

    // Normalize coefficients (a[0] is 1.0 for np.poly, but be exact).
    const float inv = 1.0f / ac[0];
    const float b0  = bc[0] * inv;
    float bt[8], nat[8];
#pragma unroll
    for (int i = 0; i < 8; ++i) {
        bt[i]  = bc[i + 1] * inv;
        nat[i] = -(ac[i + 1] * inv);
    }

    // DF2T state, zero-initialized (matches reference zero initial state;
    // chunk 0 starts exactly at t=0 so it is exact, others are warmed up).
    float z[8];
#pragma unroll
    for (int i = 0; i < 8; ++i) z[i] = 0.0f;

    const int tBase = chunk * CHUNK;
    const int tEnd  = tBase + CHUNK;
    int t0 = tBase - WARM;
    if (t0 < 0) t0 = 0;         // chunk 0: zero input+zero state == exact skip

    auto ld = [&](int tg) -> float4 {
        const float* p = (DIR == 0) ? (xr + tg) : (xr + (T - 4 - tg));
        return *(const float4*)p;
    };

    auto step = [&](float xv) -> float {
        const float yv = fmaf(b0, xv, z[0]);
#pragma unroll
        for (int i = 0; i < 7; ++i)
            z[i] = fmaf(nat[i], yv, fmaf(bt[i], xv, z[i + 1]));
        z[7] = fmaf(nat[7], yv, bt[7] * xv);
        return yv;
    };

    // 1-batch-ahead prefetch: while computing a 16-sample batch, the next
    // batch's 4 float4 loads are in flight; with 8 waves/SIMD the remaining
    // latency is hidden by TLP.
    const int nb = (tEnd - t0) / BATCH;
    float4 v[4], vn[4];
#pragma unroll
    for (int j = 0; j < 4; ++j) v[j] = ld(t0 + 4 * j);

    int t = t0;
    for (int b = 0; b < nb; ++b) {
        const int tn = t + BATCH;
        if (tn < tEnd) {
#pragma unroll
            for (int j = 0; j < 4; ++j) vn[j] = ld(tn + 4 * j);
        }

#pragma unroll
        for (int j = 0; j < 4; ++j) {
            float xs0, xs1, xs2, xs3;
            if (DIR == 0) { xs0 = v[j].x; xs1 = v[j].y; xs2 = v[j].z; xs3 = v[j].w; }
            else          { xs0 = v[j].w; xs1 = v[j].z; xs2 = v[j].y; xs3 = v[j].x; }

            const float y0 = step(xs0);
            const float y1 = step(xs1);
            const float y2 = step(xs2);
            const float y3 = step(xs3);

            const int tj = t + 4 * j;
            if (tj >= tBase) {   // WARM and CHUNK are multiples of 4: aligned
                float4 o;
                if (DIR == 0) {
                    o.x = y0; o.y = y1; o.z = y2; o.w = y3;
                    *(float4*)(yr + tj) = o;
                } else {
                    o.x = y3; o.y = y2; o.z = y1; o.w = y0;
                    *(float4*)(yr + (T - 4 - tj)) = o;
                }
            }
        }

#pragma unroll
        for (int j = 0; j < 4; ++j) v[j] = vn[j];
        t = tn;
    }
}

extern "C" void kernel_launch(void* const* d_in, const int* in_sizes, int n_in,
                              void* d_out, int out_size, void* d_ws, size_t ws_size,
                              hipStream_t stream)
{
    const float* x = (const float*)d_in[0];
    const float* b = (const float*)d_in[1];
    const float* a = (const float*)d_in[2];
    float* out = (float*)d_out;
    float* tmp = (float*)d_ws;   // forward-pass intermediate: out_size floats

    const int T = 65536;
    const int B = in_sizes[0] / T;
    const int chunksPerRow = T / CHUNK;        // 1024
    const int totalThreads = B * chunksPerRow; // 524288

    dim3 block(256);
    dim3 grid(totalThreads / 256);

    iir_pass<0><<<grid, block, 0, stream>>>(x,   tmp, b, a, T, chunksPerRow);
    iir_pass<1><<<grid, block, 0, stream>>>(tmp, out, b, a, T, chunksPerRow);
}

// Round 2
// 371.475 us; speedup vs baseline: 1.1828x; 1.1828x over previous
//
#include <hip/hip_runtime.h>

// IIR filtfilt via overlap-chunk parallelization with LDS block-tiling.
//
// R4: R3 was traffic-bound: warm-up redundancy (2.5x) was paid in HBM bytes
// (FETCH 262MB vs 128MB ideal/pass) because L1 (32KB) can't hold the 256KB
// per-CU streaming frontier; strided float4 stores also cost 1.8x WRITE_SIZE.
// Fix: each 256-thread block stages one contiguous 16384-sample tile in LDS
// (64KB) with coalesced loads; warm-up reads come from LDS (free); outputs
// are staged back through LDS and written fully coalesced.
// XOR swizzle f^((f>>4)&7) on float4 slots kills the 256B-stride bank
// conflicts of the compute-phase reads (spreads 64 lanes over 8 bank groups).
//
// Max pole radius ~0.924 -> WARM=96 truncates initial-state error to
// ~0.924^96 ~ 5e-4 relative, far below the 6e-2 threshold (absmax 0.0156).
constexpr int CHUNK = 64;              // output samples per thread
constexpr int WARM  = 96;              // warm-up samples (discarded)
constexpr int BLOCK = 256;             // threads per block
constexpr int TILE  = BLOCK * CHUNK;   // 16384 samples per block tile
constexpr int TILE_F4 = TILE / 4;      // 4096 float4 slots = 64 KB LDS

// Bank-conflict swizzle on float4-slot index (involution, stays in range).
__device__ __forceinline__ int sw(int f) { return f ^ ((f >> 4) & 7); }

// DIR=0: forward in time. DIR=1: process time-reversed sequence
// (pass-time s corresponds to forward index T-1-s).
template <int DIR>
__global__ __launch_bounds__(BLOCK, 2) void iir_pass(
    const float* __restrict__ x, float* __restrict__ y,
    const float* __restrict__ bc, const float* __restrict__ ac,
    int T, int tilesPerRow)
{
    __shared__ float4 lds[TILE_F4];    // 64 KB: input tile, then output tile

    const int tid     = threadIdx.x;
    const int row     = blockIdx.x / tilesPerRow;
    const int tileIdx = blockIdx.x - row * tilesPerRow;
    const int tileStart = tileIdx * TILE;          // pass-time coordinate

    const float* __restrict__ xr = x + (size_t)row * T;
    float* __restrict__       yr = y + (size_t)row * T;

    // Load a time-ordered quad of pass-time samples [s, s+3]. s multiple of 4.
    // s < 0 (only before the first tile) -> zeros (matches zero initial state).
    auto ld4 = [&](int s) -> float4 {
        if (s < 0) return float4{0.f, 0.f, 0.f, 0.f};
        if (DIR == 0) return *(const float4*)(xr + s);
        float4 v = *(const float4*)(xr + (T - 4 - s));
        return float4{v.w, v.z, v.y, v.x};         // reverse to time order
    };

    // ---- stage input tile into LDS (coalesced) ----
#pragma unroll
    for (int k = 0; k < TILE_F4 / BLOCK; ++k) {    // 16 iterations
        const int f = k * BLOCK + tid;
        lds[sw(f)] = ld4(tileStart + 4 * f);
    }

    // ---- coefficients (normalize; a[0] is 1.0 for np.poly, but be exact) ----
    const float inv = 1.0f / ac[0];
    const float b0  = bc[0] * inv;
    float bt[8], nat[8];
#pragma unroll
    for (int i = 0; i < 8; ++i) {
        bt[i]  = bc[i + 1] * inv;
        nat[i] = -(ac[i + 1] * inv);
    }

    // DF2T state, zero-initialized.
    float z[8];
#pragma unroll
    for (int i = 0; i < 8; ++i) z[i] = 0.0f;

    auto step = [&](float xv) -> float {
        const float yv = fmaf(b0, xv, z[0]);
#pragma unroll
        for (int i = 0; i < 7; ++i)
            z[i] = fmaf(nat[i], yv, fmaf(bt[i], xv, z[i + 1]));
        z[7] = fmaf(nat[7], yv, bt[7] * xv);
        return yv;
    };

    // ---- pre-tile warm-up from global (threads 0,1 only: 24 / 8 quads) ----
    const int wstart = tid * CHUNK - WARM;         // LDS-sample coords
    for (int s = wstart; s < 0; s += 4) {
        const float4 q = ld4(tileStart + s);
        step(q.x); step(q.y); step(q.z); step(q.w);
    }

    __syncthreads();                               // input tile ready

    // ---- in-tile warm-up from LDS (0 / 16 / 24 quads) ----
    const int fMain = tid * (CHUNK / 4);           // first main quad slot
    const int f0 = (wstart > 0 ? wstart : 0) >> 2;
#pragma unroll 8
    for (int f = f0; f < fMain; ++f) {
        const float4 q = lds[sw(f)];
        step(q.x); step(q.y); step(q.z); step(q.w);
    }

    // ---- main: 64 output samples into registers ----
    float4 out[CHUNK / 4];
#pragma unroll
    for (int j = 0; j < CHUNK / 4; ++j) {
        const float4 q = lds[sw(fMain + j)];
        float4 o;
        o.x = step(q.x); o.y = step(q.y); o.z = step(q.z); o.w = step(q.w);
        out[j] = o;
    }

    __syncthreads();                               // everyone done reading input

    // ---- dump outputs through LDS ----
#pragma unroll
    for (int j = 0; j < CHUNK / 4; ++j) lds[sw(fMain + j)] = out[j];

    __syncthreads();                               // output tile ready

    // ---- coalesced store ----
#pragma unroll
    for (int k = 0; k < TILE_F4 / BLOCK; ++k) {
        const int f = k * BLOCK + tid;
        const float4 q = lds[sw(f)];
        if (DIR == 0) {
            *(float4*)(yr + tileStart + 4 * f) = q;
        } else {
            const float4 r{q.w, q.z, q.y, q.x};
            *(float4*)(yr + (T - 4 - (tileStart + 4 * f))) = r;
        }
    }
}

extern "C" void kernel_launch(void* const* d_in, const int* in_sizes, int n_in,
                              void* d_out, int out_size, void* d_ws, size_t ws_size,
                              hipStream_t stream)
{
    const float* x = (const float*)d_in[0];
    const float* b = (const float*)d_in[1];
    const float* a = (const float*)d_in[2];
    float* out = (float*)d_out;
    float* tmp = (float*)d_ws;   // forward-pass intermediate: out_size floats

    const int T = 65536;
    const int B = in_sizes[0] / T;
    const int tilesPerRow = T / TILE;              // 4
    const int totalBlocks = B * tilesPerRow;       // 2048

    dim3 block(BLOCK);
    dim3 grid(totalBlocks);

    iir_pass<0><<<grid, block, 0, stream>>>(x,   tmp, b, a, T, tilesPerRow);
    iir_pass<1><<<grid, block, 0, stream>>>(tmp, out, b, a, T, tilesPerRow);
}

// Round 3
// 307.694 us; speedup vs baseline: 1.4280x; 1.2073x over previous
//
#include <hip/hip_runtime.h>

// IIR filtfilt via overlap-chunk parallelization with LDS block-tiling.
//
// R5: R4 was phase-serialization bound: 64KB LDS -> 2 blocks/CU (20% occ),
// and the pre-tile warm-up was a serial global-load chain on threads 0/1
// that the whole block waited on at the barrier (runtime loop bounds -> no
// pipelining, ~24 x 600cyc). Fix: stage the WARM region as part of the tile
// (tile = [tileStart-96, tileStart+8192), 33KB LDS) so ALL warm reads come
// from LDS through the coalesced staging loop, and halve the tile so 4
// blocks/CU are resident (16 waves/CU) to overlap stage/compute/store
// phases across blocks. Warm redundancy is 4x compute (cheap, VALU idle)
// but only 1.2% extra HBM bytes.
//
// Swizzle g^((g>>3)&7) on float4 slots: compute reads have stride 8 quads
// (128B) across lanes -> without swizzle all 64 lanes hit one bank group.
// XOR of (g>>3)&7 into the low bits makes every 8 consecutive lanes cover
// all 8 bank groups (2 lanes/bank = free per m136), for both the staging
// writes (consecutive g) and the compute reads (strided g).
//
// Max pole radius ~0.924 -> WARM=96 truncates initial-state error to
// ~0.924^96 ~ 5e-4 relative, far below the 6e-2 threshold (absmax 0.0156).
constexpr int CHUNK   = 32;              // output samples per thread
constexpr int WARM    = 96;              // warm-up samples (discarded)
constexpr int BLOCK   = 256;             // threads per block
constexpr int TILE    = BLOCK * CHUNK;   // 8192 samples per block tile
constexpr int WARM_Q  = WARM / 4;        // 24 warm quads
constexpr int TILE_Q  = TILE / 4;        // 2048 output quads
constexpr int STAGE_Q = TILE_Q + WARM_Q; // 2072 staged quads = 33152 B LDS
constexpr int QPT     = CHUNK / 4;       // 8 output quads per thread

// Bank-conflict swizzle on float4-slot index (involution, low-3-bit XOR).
__device__ __forceinline__ int sw(int g) { return g ^ ((g >> 3) & 7); }

// DIR=0: forward in time. DIR=1: process time-reversed sequence
// (pass-time s corresponds to forward index T-1-s).
template <int DIR>
__global__ __launch_bounds__(BLOCK, 4) void iir_pass(
    const float* __restrict__ x, float* __restrict__ y,
    const float* __restrict__ bc, const float* __restrict__ ac,
    int T, int tilesPerRow)
{
    __shared__ float4 lds[STAGE_Q];    // 33 KB: staged input, then output

    const int tid     = threadIdx.x;
    const int row     = blockIdx.x / tilesPerRow;
    const int tileIdx = blockIdx.x - row * tilesPerRow;
    const int tileStart = tileIdx * TILE;          // pass-time coordinate

    const float* __restrict__ xr = x + (size_t)row * T;
    float* __restrict__       yr = y + (size_t)row * T;

    // Load a time-ordered quad of pass-time samples [s, s+3]. s multiple of 4.
    // s < 0 (head of tile 0's warm region) -> zeros == exact zero init state.
    auto ld4 = [&](int s) -> float4 {
        if (s < 0) return float4{0.f, 0.f, 0.f, 0.f};
        if (DIR == 0) return *(const float4*)(xr + s);
        float4 v = *(const float4*)(xr + (T - 4 - s));
        return float4{v.w, v.z, v.y, v.x};         // reverse to time order
    };

    // ---- stage [tileStart-WARM, tileStart+TILE) into LDS (coalesced) ----
#pragma unroll
    for (int k = 0; k < (STAGE_Q + BLOCK - 1) / BLOCK; ++k) {  // 9 iterations
        const int g = k * BLOCK + tid;
        if (g < STAGE_Q) lds[sw(g)] = ld4(tileStart - WARM + 4 * g);
    }

    // ---- coefficients (normalize; a[0] is 1.0 for np.poly, but be exact) ----
    const float inv = 1.0f / ac[0];
    const float b0  = bc[0] * inv;
    float bt[8], nat[8];
#pragma unroll
    for (int i = 0; i < 8; ++i) {
        bt[i]  = bc[i + 1] * inv;
        nat[i] = -(ac[i + 1] * inv);
    }

    // DF2T state, zero-initialized.
    float z[8];
#pragma unroll
    for (int i = 0; i < 8; ++i) z[i] = 0.0f;

    auto step = [&](float xv) -> float {
        const float yv = fmaf(b0, xv, z[0]);
#pragma unroll
        for (int i = 0; i < 7; ++i)
            z[i] = fmaf(nat[i], yv, fmaf(bt[i], xv, z[i + 1]));
        z[7] = fmaf(nat[7], yv, bt[7] * xv);
        return yv;
    };

    __syncthreads();                               // staged tile ready

    // ---- warm-up: 24 quads from LDS (uniform across all threads) ----
    const int gw = tid * QPT;                      // thread's first staged quad
#pragma unroll
    for (int i = 0; i < WARM_Q; ++i) {
        const float4 q = lds[sw(gw + i)];
        step(q.x); step(q.y); step(q.z); step(q.w);
    }

    // ---- main: 32 output samples into registers ----
    float4 out[QPT];
#pragma unroll
    for (int j = 0; j < QPT; ++j) {
        const float4 q = lds[sw(gw + WARM_Q + j)];
        float4 o;
        o.x = step(q.x); o.y = step(q.y); o.z = step(q.z); o.w = step(q.w);
        out[j] = o;
    }

    __syncthreads();                               // everyone done reading input

    // ---- dump outputs through LDS (output quad oq = tid*QPT + j) ----
#pragma unroll
    for (int j = 0; j < QPT; ++j) lds[sw(gw + j)] = out[j];

    __syncthreads();                               // output tile ready

    // ---- coalesced store ----
#pragma unroll
    for (int k = 0; k < TILE_Q / BLOCK; ++k) {     // 8 iterations
        const int q = k * BLOCK + tid;
        const float4 v = lds[sw(q)];
        const int s = tileStart + 4 * q;
        if (DIR == 0) {
            *(float4*)(yr + s) = v;
        } else {
            *(float4*)(yr + (T - 4 - s)) = float4{v.w, v.z, v.y, v.x};
        }
    }
}

extern "C" void kernel_launch(void* const* d_in, const int* in_sizes, int n_in,
                              void* d_out, int out_size, void* d_ws, size_t ws_size,
                              hipStream_t stream)
{
    const float* x = (const float*)d_in[0];
    const float* b = (const float*)d_in[1];
    const float* a = (const float*)d_in[2];
    float* out = (float*)d_out;
    float* tmp = (float*)d_ws;   // forward-pass intermediate: out_size floats

    const int T = 65536;
    const int B = in_sizes[0] / T;
    const int tilesPerRow = T / TILE;              // 8
    const int totalBlocks = B * tilesPerRow;       // 4096

    dim3 block(BLOCK);
    dim3 grid(totalBlocks);

    iir_pass<0><<<grid, block, 0, stream>>>(x,   tmp, b, a, T, tilesPerRow);
    iir_pass<1><<<grid, block, 0, stream>>>(tmp, out, b, a, T, tilesPerRow);
}